// Round 4
// baseline (431.025 us; speedup 1.0000x reference)
//
#include <hip/hip_runtime.h>

// Problem constants: B=8, S=4096, H=8, D=128
// MAX_TOTAL = B*S = 32768 output cache rows per cache; row = 1024 f32 = 4 KB.
#define BB 8
#define SS 4096
#define ROW_F4 256             // float4 per row
#define MAX_TOTAL 32768
#define NTASKS (2 * MAX_TOTAL) // k rows then v rows
#define GRID 2048
#define MLP 8                  // 65536 tasks = 4 iters * MLP * GRID exactly

// True clang vector type (nontemporal builtins reject HIP_vector_type).
typedef float f32x4 __attribute__((ext_vector_type(4)));

__global__ __launch_bounds__(256) void pack_kv_kernel(
    const f32x4* __restrict__ kin,
    const f32x4* __restrict__ vin,
    const int*   __restrict__ seq,
    f32x4* __restrict__ kout,
    f32x4* __restrict__ vout,
    float* __restrict__ meta)   // meta[0..7]=seq_lens, meta[8..16]=cumsum(9)
{
    // Tiny uniform cumsum (seq is 8 ints, L2-hot scalar loads).
    int cum[BB + 1];
    cum[0] = 0;
#pragma unroll
    for (int b = 0; b < BB; ++b) cum[b + 1] = cum[b] + seq[b];

    if (blockIdx.x == 0 && threadIdx.x < (BB + BB + 1)) {
        int t = threadIdx.x;
        if (t < BB) meta[t] = (float)seq[t];
        else        meta[t] = (float)cum[t - BB];   // meta[8+i] = cum[i]
    }

    const f32x4 zero = (f32x4)(0.f);
    const int elem  = threadIdx.x;   // float4 index within the 4 KB row
    const int total = cum[BB];       // ragged total rows (<= 32768)
    const int g     = gridDim.x;     // == GRID

    // 8-deep batched loads (regular, may hit L3 from the fresh d_in restore),
    // then 8 nontemporal stores (no-allocate: don't pollute L2/L3 with
    // stream-out data). 8 KB in flight per wave.
    for (int t0 = blockIdx.x; t0 < NTASKS; t0 += MLP * g) {
        f32x4 v[MLP];
#pragma unroll
        for (int u = 0; u < MLP; ++u) {
            const int task = t0 + u * g;
            const int row  = task & (MAX_TOTAL - 1);
            v[u] = zero;
            if (row < total) {
                const f32x4* __restrict__ in = (task < MAX_TOTAL) ? kin : vin;
                int b = 0;
#pragma unroll
                for (int i = 1; i < BB; ++i) b += (row >= cum[i]);
                const int t = row - cum[b];
                v[u] = in[((size_t)b * SS + (size_t)t) * ROW_F4 + elem];
            }
        }
#pragma unroll
        for (int u = 0; u < MLP; ++u) {
            const int task = t0 + u * g;
            const int row  = task & (MAX_TOTAL - 1);
            f32x4* __restrict__ out = (task < MAX_TOTAL) ? kout : vout;
            __builtin_nontemporal_store(v[u], &out[(size_t)row * ROW_F4 + elem]);
        }
    }
}

extern "C" void kernel_launch(void* const* d_in, const int* in_sizes, int n_in,
                              void* d_out, int out_size, void* d_ws, size_t ws_size,
                              hipStream_t stream) {
    const f32x4* kin = (const f32x4*)d_in[0];
    const f32x4* vin = (const f32x4*)d_in[1];
    const int*   seq = (const int*)d_in[2];

    float* out = (float*)d_out;
    const size_t NK = (size_t)MAX_TOTAL * 1024;   // floats per cache
    f32x4* kout = (f32x4*)out;
    f32x4* vout = (f32x4*)(out + NK);
    float* meta = out + 2 * NK;                   // 8 seq_lens + 9 cumsum

    hipLaunchKernelGGL(pack_kv_kernel, dim3(GRID), dim3(256), 0, stream,
                       kin, vin, seq, kout, vout, meta);
}